// Round 8
// baseline (337.734 us; speedup 1.0000x reference)
//
#include <hip/hip_runtime.h>

#define NE 8
#define CAP 1024
#define HD 1024
#define ID 1408
#define TT 2048

typedef __attribute__((ext_vector_type(8))) short bf16x8;
typedef __attribute__((ext_vector_type(4))) float f32x4;
typedef unsigned short u16;
typedef unsigned int u32;
typedef unsigned long long u64;

__device__ __forceinline__ u16 f2bf(float f) {
  u32 u = __float_as_uint(f);
  u = (u + 0x7fffu + ((u >> 16) & 1u)) >> 16;
  return (u16)u;
}
__device__ __forceinline__ u32 pk2(float a, float b) {
  return (u32)f2bf(a) | ((u32)f2bf(b) << 16);
}

__device__ __forceinline__ void async_cp16(const void* g, void* l) {
  __builtin_amdgcn_global_load_lds(
      (const __attribute__((address_space(1))) u32*)g,
      (__attribute__((address_space(3))) u32*)l, 16, 0, 0);
}

// ------- x fp32->bf16 convert + d_out zero (same elem count), one pass -------
__global__ void cvt_x_zero_kernel(const float4* __restrict__ src, ushort4* __restrict__ dst,
                                  float4* __restrict__ out, int n4) {
  int i = blockIdx.x * 256 + threadIdx.x;
  if (i >= n4) return;
  float4 v = src[i];
  ushort4 o;
  o.x = f2bf(v.x); o.y = f2bf(v.y); o.z = f2bf(v.z); o.w = f2bf(v.w);
  dst[i] = o;
  out[i] = float4{0.f, 0.f, 0.f, 0.f};
}

// ---------------- routing: exact flat-order cumsum positions ----------------
__global__ void route_kernel(const int* __restrict__ ids, int* __restrict__ rowmap,
                             int* __restrict__ flatpos, int* __restrict__ counts) {
  __shared__ int ids_s[TT * 2];
  __shared__ int sc[256][NE + 1];
  int tid = threadIdx.x;
  for (int i = tid; i < TT * 2; i += 256) ids_s[i] = ids[i];
  __syncthreads();
  int base = tid * 16;
  u64 own64 = 0;
#pragma unroll
  for (int j = 0; j < 16; ++j) own64 += 1ull << (ids_s[base + j] * 8);
  int own[NE];
#pragma unroll
  for (int e = 0; e < NE; ++e) { own[e] = (int)((own64 >> (e * 8)) & 0xff); sc[tid][e] = own[e]; }
  __syncthreads();
  for (int off = 1; off < 256; off <<= 1) {
    int v[NE];
    if (tid >= off) {
#pragma unroll
      for (int e = 0; e < NE; ++e) v[e] = sc[tid - off][e];
    }
    __syncthreads();
    if (tid >= off) {
#pragma unroll
      for (int e = 0; e < NE; ++e) sc[tid][e] += v[e];
    }
    __syncthreads();
  }
  if (tid == 255) {
#pragma unroll
    for (int e = 0; e < NE; ++e) counts[e] = sc[255][e] < CAP ? sc[255][e] : CAP;
  }
  int excl[NE];
#pragma unroll
  for (int e = 0; e < NE; ++e) excl[e] = sc[tid][e] - own[e];
  __syncthreads();
#pragma unroll
  for (int e = 0; e < NE; ++e) sc[tid][e] = excl[e];
#pragma unroll
  for (int j = 0; j < 16; ++j) {
    int f = base + j;
    int e = ids_s[f];
    int p = sc[tid][e]++;
    if (p < CAP) { rowmap[e * CAP + p] = f; flatpos[f] = p; }
    else flatpos[f] = -1;
  }
}

// --------- GEMM1: gathered x(bf16) . w1(fp32, inline cvt)^T, fused SiLU ------
// 64x128 tile, 4 waves (2x2 of 32x64), BK=64. A staged async (global_load_lds
// 16B); B loaded fp32 -> f2bf pack -> ds_write_b128 (conversion fused; the
// standalone cvt_w1 pass and its 138 MB of HBM streaming are gone).
// Gate/up group-16 interleave applied via B row-index mapping:
//   interleaved row nIl -> orig w1 row: grp=nIl>>5, w=nIl&31,
//   w<16 ? grp*16+w (gate) : ID + grp*16 + w-16 (up).
// Epilogue: same-lane silu(gate)*up (ni even/odd), LDS repack, 16B stores.
__global__ __launch_bounds__(256) void gemm1_kernel(
    const u16* __restrict__ A, const float* __restrict__ W1, u16* __restrict__ Hb,
    const int* __restrict__ rowmap, const int* __restrict__ counts) {
  int e = blockIdx.x;
  int count = counts[e];
  int m0 = blockIdx.y * 64;
  if (m0 >= count) return;
  int n0 = blockIdx.z * 128;
  int tid = threadIdx.x;
  int lane = tid & 63, wid = tid >> 6;
  int wm = wid >> 1, wn = wid & 1;
  int q = lane >> 4, lm = lane & 15;

  __shared__ __align__(16) char smA[64 * 128];    // 8 KB
  __shared__ __align__(16) char smB[128 * 128];   // 16 KB

  int rloc = tid >> 3;
  int chs = ((tid & 7) ^ (rloc & 7)) * 8;  // swizzled elem offset in 64-elem k-tile
  const u16* aP[2];
  const float* bPf[4];
#pragma unroll
  for (int i = 0; i < 2; ++i) {
    int gr = m0 + rloc + 32 * i;
    int f = (gr < count) ? rowmap[e * CAP + gr] : 0;
    aP[i] = A + (size_t)(f >> 1) * HD + chs;
  }
#pragma unroll
  for (int i = 0; i < 4; ++i) {
    int nIl = n0 + rloc + 32 * i;
    int grp = nIl >> 5, w = nIl & 31;
    int orig = (w < 16) ? (grp * 16 + w) : (ID + grp * 16 + w - 16);
    bPf[i] = W1 + ((size_t)e * 2 * ID + orig) * HD + chs;
  }

  f32x4 zero = {0.f, 0.f, 0.f, 0.f};
  f32x4 acc[2][4];
#pragma unroll
  for (int mi = 0; mi < 2; ++mi)
#pragma unroll
    for (int ni = 0; ni < 4; ++ni) acc[mi][ni] = zero;

  for (int kt = 0; kt < HD / 64; ++kt) {
    int ko = kt * 64;
    // B: fp32 loads first (longest dependency chain)
    float4 f0[4], f1[4];
#pragma unroll
    for (int i = 0; i < 4; ++i) {
      f0[i] = *(const float4*)(bPf[i] + ko);
      f1[i] = *(const float4*)(bPf[i] + ko + 4);
    }
    // A: async direct-to-LDS
#pragma unroll
    for (int i = 0; i < 2; ++i)
      async_cp16(aP[i] + ko, smA + (i * 256 + tid) * 16);
    // B: convert + LDS write
#pragma unroll
    for (int i = 0; i < 4; ++i) {
      uint4 pk;
      pk.x = pk2(f0[i].x, f0[i].y); pk.y = pk2(f0[i].z, f0[i].w);
      pk.z = pk2(f1[i].x, f1[i].y); pk.w = pk2(f1[i].z, f1[i].w);
      *(uint4*)(smB + (i * 256 + tid) * 16) = pk;
    }
    asm volatile("s_waitcnt vmcnt(0)" ::: "memory");
    __syncthreads();
#pragma unroll
    for (int s = 0; s < 2; ++s) {
      bf16x8 af[2], bfr[4];
#pragma unroll
      for (int mi = 0; mi < 2; ++mi) {
        int row = wm * 32 + mi * 16 + lm;
        af[mi] = *(const bf16x8*)(smA + row * 128 + (((s * 4 + q) ^ (lm & 7)) * 16));
      }
#pragma unroll
      for (int ni = 0; ni < 4; ++ni) {
        int row = wn * 64 + ni * 16 + lm;
        bfr[ni] = *(const bf16x8*)(smB + row * 128 + (((s * 4 + q) ^ (lm & 7)) * 16));
      }
#pragma unroll
      for (int mi = 0; mi < 2; ++mi)
#pragma unroll
        for (int ni = 0; ni < 4; ++ni)
          acc[mi][ni] = __builtin_amdgcn_mfma_f32_16x16x32_bf16(af[mi], bfr[ni], acc[mi][ni], 0, 0, 0);
    }
    __syncthreads();
  }

  // ---- fused SiLU epilogue: merged 64x64 u16 tile via LDS repack ----
  u16* smOut = (u16*)smB;  // [64][72] u16 (stride 72: 16B-aligned, conflict-free)
#pragma unroll
  for (int mi = 0; mi < 2; ++mi) {
#pragma unroll
    for (int k = 0; k < 2; ++k) {
      int colL = wn * 32 + k * 16 + lm;
#pragma unroll
      for (int r = 0; r < 4; ++r) {
        float g = acc[mi][2 * k][r];
        float u = acc[mi][2 * k + 1][r];
        float a = g / (1.f + __expf(-g)) * u;
        int row = wm * 32 + mi * 16 + q * 4 + r;
        smOut[row * 72 + colL] = f2bf(a);
      }
    }
  }
  __syncthreads();
  {
    int row = tid >> 2, seg = tid & 3;           // seg = 16-u16 segment
    const u16* sp = smOut + row * 72 + seg * 16;
    bf16x8 v0 = *(const bf16x8*)sp;
    bf16x8 v1 = *(const bf16x8*)(sp + 8);
    u16* dp = Hb + ((size_t)e * CAP + m0 + row) * ID + (n0 >> 1) + seg * 16;
    *(bf16x8*)dp = v0;
    *(bf16x8*)(dp + 8) = v1;
  }
}

// ------ GEMM2: act(bf16) . w2(fp32, inline cvt)^T, fused combine, 64x64 ------
__global__ __launch_bounds__(256) void gemm2_kernel(
    const u16* __restrict__ A, const float* __restrict__ W2, float* __restrict__ out,
    const int* __restrict__ rowmap, const int* __restrict__ counts,
    const float* __restrict__ tw) {
  int e = blockIdx.x;
  int count = counts[e];
  int m0 = blockIdx.y * 64;
  if (m0 >= count) return;
  int n0 = blockIdx.z * 64;
  int tid = threadIdx.x;
  int lane = tid & 63, wid = tid >> 6;
  int wm = wid >> 1, wn = wid & 1;
  int q = lane >> 4, lm = lane & 15;

  __shared__ __align__(16) char smA[64 * 128];  // 8 KB
  __shared__ __align__(16) char smB[64 * 128];  // 8 KB

  int rloc = tid >> 3;
  int chs = ((tid & 7) ^ (rloc & 7)) * 8;
  const u16* aP[2];
  const float* bPf[2];
#pragma unroll
  for (int i = 0; i < 2; ++i) {
    aP[i] = A + ((size_t)e * CAP + m0 + rloc + 32 * i) * ID + chs;
    bPf[i] = W2 + ((size_t)e * HD + n0 + rloc + 32 * i) * ID + chs;
  }

  f32x4 zero = {0.f, 0.f, 0.f, 0.f};
  f32x4 acc[2][2];
#pragma unroll
  for (int mi = 0; mi < 2; ++mi)
#pragma unroll
    for (int ni = 0; ni < 2; ++ni) acc[mi][ni] = zero;

  for (int kt = 0; kt < ID / 64; ++kt) {
    int ko = kt * 64;
    float4 f0[2], f1[2];
#pragma unroll
    for (int i = 0; i < 2; ++i) {
      f0[i] = *(const float4*)(bPf[i] + ko);
      f1[i] = *(const float4*)(bPf[i] + ko + 4);
    }
#pragma unroll
    for (int i = 0; i < 2; ++i)
      async_cp16(aP[i] + ko, smA + (i * 256 + tid) * 16);
#pragma unroll
    for (int i = 0; i < 2; ++i) {
      uint4 pk;
      pk.x = pk2(f0[i].x, f0[i].y); pk.y = pk2(f0[i].z, f0[i].w);
      pk.z = pk2(f1[i].x, f1[i].y); pk.w = pk2(f1[i].z, f1[i].w);
      *(uint4*)(smB + (i * 256 + tid) * 16) = pk;
    }
    asm volatile("s_waitcnt vmcnt(0)" ::: "memory");
    __syncthreads();
#pragma unroll
    for (int s = 0; s < 2; ++s) {
      bf16x8 af[2], bfr[2];
#pragma unroll
      for (int mi = 0; mi < 2; ++mi) {
        int row = wm * 32 + mi * 16 + lm;
        af[mi] = *(const bf16x8*)(smA + row * 128 + (((s * 4 + q) ^ (lm & 7)) * 16));
      }
#pragma unroll
      for (int ni = 0; ni < 2; ++ni) {
        int row = wn * 32 + ni * 16 + lm;
        bfr[ni] = *(const bf16x8*)(smB + row * 128 + (((s * 4 + q) ^ (lm & 7)) * 16));
      }
#pragma unroll
      for (int mi = 0; mi < 2; ++mi)
#pragma unroll
        for (int ni = 0; ni < 2; ++ni)
          acc[mi][ni] = __builtin_amdgcn_mfma_f32_16x16x32_bf16(af[mi], bfr[ni], acc[mi][ni], 0, 0, 0);
    }
    __syncthreads();
  }

  // fused combine epilogue: out[token, col] += w * y
#pragma unroll
  for (int mi = 0; mi < 2; ++mi) {
#pragma unroll
    for (int r = 0; r < 4; ++r) {
      int grow = m0 + wm * 32 + mi * 16 + q * 4 + r;
      if (grow < count) {
        int f = rowmap[e * CAP + grow];
        float w = tw[f];
        int t = f >> 1;
#pragma unroll
        for (int ni = 0; ni < 2; ++ni) {
          int col = n0 + wn * 32 + ni * 16 + lm;
          atomicAdd(&out[(size_t)t * HD + col], w * acc[mi][ni][r]);
        }
      }
    }
  }
}

extern "C" void kernel_launch(void* const* d_in, const int* in_sizes, int n_in,
                              void* d_out, int out_size, void* d_ws, size_t ws_size,
                              hipStream_t stream) {
  const float* hidden = (const float*)d_in[0];
  const float* w1 = (const float*)d_in[1];
  const float* w2 = (const float*)d_in[2];
  const float* tw = (const float*)d_in[3];
  const int* ids = (const int*)d_in[4];
  float* out = (float*)d_out;

  char* p = (char*)d_ws;
  auto alloc = [&](size_t b) { char* r = p; p += (b + 255) & ~(size_t)255; return r; };
  u16* bx = (u16*)alloc((size_t)TT * HD * 2);          // 4.2 MB
  u16* hbuf = (u16*)alloc((size_t)NE * CAP * ID * 2);  // 23.1 MB
  int* rowmap = (int*)alloc((size_t)NE * CAP * 4);
  int* flatpos = (int*)alloc((size_t)TT * 2 * 4);
  int* counts = (int*)alloc((size_t)NE * 4);

  int n4 = TT * HD / 4;
  cvt_x_zero_kernel<<<(n4 + 255) / 256, 256, 0, stream>>>(
      (const float4*)hidden, (ushort4*)bx, (float4*)out, n4);

  route_kernel<<<1, 256, 0, stream>>>(ids, rowmap, flatpos, counts);

  // GEMM1 + SiLU (w1 cvt fused): hbuf = silu(x.w1g^T) * (x.w1u^T)
  gemm1_kernel<<<dim3(NE, CAP / 64, 2 * ID / 128), 256, 0, stream>>>(
      bx, w1, hbuf, rowmap, counts);

  // GEMM2 + combine (w2 cvt fused): out[t,:] += w * (act . w2^T)
  gemm2_kernel<<<dim3(NE, CAP / 64, HD / 64), 256, 0, stream>>>(
      hbuf, w2, out, rowmap, counts, tw);
}

// Round 9
// 265.787 us; speedup vs baseline: 1.2707x; 1.2707x over previous
//
#include <hip/hip_runtime.h>

#define NE 8
#define CAP 1024
#define HD 1024
#define ID 1408
#define TT 2048

typedef __attribute__((ext_vector_type(8))) short bf16x8;
typedef __attribute__((ext_vector_type(4))) float f32x4;
typedef unsigned short u16;
typedef unsigned int u32;
typedef unsigned long long u64;

__device__ __forceinline__ u16 f2bf(float f) {
  u32 u = __float_as_uint(f);
  u = (u + 0x7fffu + ((u >> 16) & 1u)) >> 16;
  return (u16)u;
}

__device__ __forceinline__ void async_cp16(const void* g, void* l) {
  __builtin_amdgcn_global_load_lds(
      (const __attribute__((address_space(1))) u32*)g,
      (__attribute__((address_space(3))) u32*)l, 16, 0, 0);
}

// ---------------- fused prep: w1 interleave-cvt + w2 cvt + x cvt + out zero ----
// One launch, grid-partitioned. All segments are pure streaming (BW-bound).
// w1: gate j -> row (j>>4)*32+(j&15), up j -> +16 (group-16 interleave so
// gemm1's acc[ni even]=gate, acc[ni odd]=up in the SAME lane).
#define W1_BLKS (2 * ID * NE)            // 22528: one block per (row,expert)
#define W2_BLKS (NE * HD * ID / 4 / 256) // 11264
#define X_BLKS (TT * HD / 4 / 256)       // 2048
__global__ void prep_kernel(const float4* __restrict__ w1, ushort4* __restrict__ bw1,
                            const float4* __restrict__ w2, ushort4* __restrict__ bw2,
                            const float4* __restrict__ x, ushort4* __restrict__ bx,
                            float4* __restrict__ out) {
  int b = blockIdx.x;
  int tid = threadIdx.x;
  if (b < W1_BLKS) {
    int n = b % (2 * ID);
    int e = b / (2 * ID);
    int j = (n < ID) ? n : (n - ID);
    int np = (j >> 4) * 32 + (j & 15) + ((n < ID) ? 0 : 16);
    float4 v = w1[((size_t)e * 2 * ID + n) * (HD / 4) + tid];
    ushort4 o;
    o.x = f2bf(v.x); o.y = f2bf(v.y); o.z = f2bf(v.z); o.w = f2bf(v.w);
    bw1[((size_t)e * 2 * ID + np) * (HD / 4) + tid] = o;
  } else if (b < W1_BLKS + W2_BLKS) {
    size_t i = (size_t)(b - W1_BLKS) * 256 + tid;
    float4 v = w2[i];
    ushort4 o;
    o.x = f2bf(v.x); o.y = f2bf(v.y); o.z = f2bf(v.z); o.w = f2bf(v.w);
    bw2[i] = o;
  } else {
    size_t i = (size_t)(b - W1_BLKS - W2_BLKS) * 256 + tid;
    float4 v = x[i];
    ushort4 o;
    o.x = f2bf(v.x); o.y = f2bf(v.y); o.z = f2bf(v.z); o.w = f2bf(v.w);
    bx[i] = o;
    out[i] = float4{0.f, 0.f, 0.f, 0.f};  // same element count as x
  }
}

// ---------------- routing: exact flat-order cumsum positions ----------------
__global__ void route_kernel(const int* __restrict__ ids, int* __restrict__ rowmap,
                             int* __restrict__ flatpos, int* __restrict__ counts) {
  __shared__ int ids_s[TT * 2];
  __shared__ int sc[256][NE + 1];
  int tid = threadIdx.x;
  for (int i = tid; i < TT * 2; i += 256) ids_s[i] = ids[i];
  __syncthreads();
  int base = tid * 16;
  u64 own64 = 0;
#pragma unroll
  for (int j = 0; j < 16; ++j) own64 += 1ull << (ids_s[base + j] * 8);
  int own[NE];
#pragma unroll
  for (int e = 0; e < NE; ++e) { own[e] = (int)((own64 >> (e * 8)) & 0xff); sc[tid][e] = own[e]; }
  __syncthreads();
  for (int off = 1; off < 256; off <<= 1) {
    int v[NE];
    if (tid >= off) {
#pragma unroll
      for (int e = 0; e < NE; ++e) v[e] = sc[tid - off][e];
    }
    __syncthreads();
    if (tid >= off) {
#pragma unroll
      for (int e = 0; e < NE; ++e) sc[tid][e] += v[e];
    }
    __syncthreads();
  }
  if (tid == 255) {
#pragma unroll
    for (int e = 0; e < NE; ++e) counts[e] = sc[255][e] < CAP ? sc[255][e] : CAP;
  }
  int excl[NE];
#pragma unroll
  for (int e = 0; e < NE; ++e) excl[e] = sc[tid][e] - own[e];
  __syncthreads();
#pragma unroll
  for (int e = 0; e < NE; ++e) sc[tid][e] = excl[e];
#pragma unroll
  for (int j = 0; j < 16; ++j) {
    int f = base + j;
    int e = ids_s[f];
    int p = sc[tid][e]++;
    if (p < CAP) { rowmap[e * CAP + p] = f; flatpos[f] = p; }
    else flatpos[f] = -1;
  }
}

// ---------------- GEMM1: gathered x . w1_il^T, fused SiLU, 64x128 tile --------
// 4 waves (2x2 of 32x64), BK=64, single-buffer K-loop, global_load_lds 16B.
// ~1400 active blocks (5.5/CU) hide the per-tile vmcnt(0)+barrier drain.
// Epilogue: same-lane silu(gate)*up (ni even/odd), LDS repack, 16B stores.
__global__ __launch_bounds__(256) void gemm1_kernel(
    const u16* __restrict__ A, const u16* __restrict__ B, u16* __restrict__ Hb,
    const int* __restrict__ rowmap, const int* __restrict__ counts) {
  int e = blockIdx.x;
  int count = counts[e];
  int m0 = blockIdx.y * 64;
  if (m0 >= count) return;
  int n0 = blockIdx.z * 128;
  int tid = threadIdx.x;
  int lane = tid & 63, wid = tid >> 6;
  int wm = wid >> 1, wn = wid & 1;
  int q = lane >> 4, lm = lane & 15;

  __shared__ __align__(16) char smA[64 * 128];    // 8 KB
  __shared__ __align__(16) char smB[128 * 128];   // 16 KB

  int rloc = tid >> 3;
  int chs = ((tid & 7) ^ (rloc & 7)) * 8;
  const u16* aP[2];
  const u16* bP[4];
#pragma unroll
  for (int i = 0; i < 2; ++i) {
    int gr = m0 + rloc + 32 * i;
    int f = (gr < count) ? rowmap[e * CAP + gr] : 0;
    aP[i] = A + (size_t)(f >> 1) * HD + chs;
  }
#pragma unroll
  for (int i = 0; i < 4; ++i)
    bP[i] = B + ((size_t)e * 2 * ID + n0 + rloc + 32 * i) * HD + chs;

  f32x4 zero = {0.f, 0.f, 0.f, 0.f};
  f32x4 acc[2][4];
#pragma unroll
  for (int mi = 0; mi < 2; ++mi)
#pragma unroll
    for (int ni = 0; ni < 4; ++ni) acc[mi][ni] = zero;

  for (int kt = 0; kt < HD / 64; ++kt) {
    int ko = kt * 64;
#pragma unroll
    for (int i = 0; i < 2; ++i)
      async_cp16(aP[i] + ko, smA + (i * 256 + tid) * 16);
#pragma unroll
    for (int i = 0; i < 4; ++i)
      async_cp16(bP[i] + ko, smB + (i * 256 + tid) * 16);
    asm volatile("s_waitcnt vmcnt(0)" ::: "memory");
    __syncthreads();
#pragma unroll
    for (int s = 0; s < 2; ++s) {
      bf16x8 af[2], bfr[4];
#pragma unroll
      for (int mi = 0; mi < 2; ++mi) {
        int row = wm * 32 + mi * 16 + lm;
        af[mi] = *(const bf16x8*)(smA + row * 128 + (((s * 4 + q) ^ (lm & 7)) * 16));
      }
#pragma unroll
      for (int ni = 0; ni < 4; ++ni) {
        int row = wn * 64 + ni * 16 + lm;
        bfr[ni] = *(const bf16x8*)(smB + row * 128 + (((s * 4 + q) ^ (lm & 7)) * 16));
      }
#pragma unroll
      for (int mi = 0; mi < 2; ++mi)
#pragma unroll
        for (int ni = 0; ni < 4; ++ni)
          acc[mi][ni] = __builtin_amdgcn_mfma_f32_16x16x32_bf16(af[mi], bfr[ni], acc[mi][ni], 0, 0, 0);
    }
    __syncthreads();
  }

  // ---- fused SiLU epilogue: merged 64x64 u16 tile via LDS repack ----
  u16* smOut = (u16*)smB;  // [64][72] u16
#pragma unroll
  for (int mi = 0; mi < 2; ++mi) {
#pragma unroll
    for (int k = 0; k < 2; ++k) {
      int colL = wn * 32 + k * 16 + lm;
#pragma unroll
      for (int r = 0; r < 4; ++r) {
        float g = acc[mi][2 * k][r];
        float u = acc[mi][2 * k + 1][r];
        float a = g / (1.f + __expf(-g)) * u;
        int row = wm * 32 + mi * 16 + q * 4 + r;
        smOut[row * 72 + colL] = f2bf(a);
      }
    }
  }
  __syncthreads();
  {
    int row = tid >> 2, seg = tid & 3;
    const u16* sp = smOut + row * 72 + seg * 16;
    bf16x8 v0 = *(const bf16x8*)sp;
    bf16x8 v1 = *(const bf16x8*)(sp + 8);
    u16* dp = Hb + ((size_t)e * CAP + m0 + row) * ID + (n0 >> 1) + seg * 16;
    *(bf16x8*)dp = v0;
    *(bf16x8*)(dp + 8) = v1;
  }
}

// ---------------- GEMM2: act . w2^T, fused combine (atomicAdd), 64x64 tile ----
__global__ __launch_bounds__(256) void gemm2_kernel(
    const u16* __restrict__ A, const u16* __restrict__ B, float* __restrict__ out,
    const int* __restrict__ rowmap, const int* __restrict__ counts,
    const float* __restrict__ tw) {
  int e = blockIdx.x;
  int count = counts[e];
  int m0 = blockIdx.y * 64;
  if (m0 >= count) return;
  int n0 = blockIdx.z * 64;
  int tid = threadIdx.x;
  int lane = tid & 63, wid = tid >> 6;
  int wm = wid >> 1, wn = wid & 1;
  int q = lane >> 4, lm = lane & 15;

  __shared__ __align__(16) char smA[64 * 128];  // 8 KB
  __shared__ __align__(16) char smB[64 * 128];  // 8 KB

  int rloc = tid >> 3;
  int chs = ((tid & 7) ^ (rloc & 7)) * 8;
  const u16* aP[2];
  const u16* bP[2];
#pragma unroll
  for (int i = 0; i < 2; ++i) {
    aP[i] = A + ((size_t)e * CAP + m0 + rloc + 32 * i) * ID + chs;
    bP[i] = B + ((size_t)e * HD + n0 + rloc + 32 * i) * ID + chs;
  }

  f32x4 zero = {0.f, 0.f, 0.f, 0.f};
  f32x4 acc[2][2];
#pragma unroll
  for (int mi = 0; mi < 2; ++mi)
#pragma unroll
    for (int ni = 0; ni < 2; ++ni) acc[mi][ni] = zero;

  for (int kt = 0; kt < ID / 64; ++kt) {
    int ko = kt * 64;
#pragma unroll
    for (int i = 0; i < 2; ++i) {
      async_cp16(aP[i] + ko, smA + (i * 256 + tid) * 16);
      async_cp16(bP[i] + ko, smB + (i * 256 + tid) * 16);
    }
    asm volatile("s_waitcnt vmcnt(0)" ::: "memory");
    __syncthreads();
#pragma unroll
    for (int s = 0; s < 2; ++s) {
      bf16x8 af[2], bfr[2];
#pragma unroll
      for (int mi = 0; mi < 2; ++mi) {
        int row = wm * 32 + mi * 16 + lm;
        af[mi] = *(const bf16x8*)(smA + row * 128 + (((s * 4 + q) ^ (lm & 7)) * 16));
      }
#pragma unroll
      for (int ni = 0; ni < 2; ++ni) {
        int row = wn * 32 + ni * 16 + lm;
        bfr[ni] = *(const bf16x8*)(smB + row * 128 + (((s * 4 + q) ^ (lm & 7)) * 16));
      }
#pragma unroll
      for (int mi = 0; mi < 2; ++mi)
#pragma unroll
        for (int ni = 0; ni < 2; ++ni)
          acc[mi][ni] = __builtin_amdgcn_mfma_f32_16x16x32_bf16(af[mi], bfr[ni], acc[mi][ni], 0, 0, 0);
    }
    __syncthreads();
  }

  // fused combine epilogue: out[token, col] += w * y
#pragma unroll
  for (int mi = 0; mi < 2; ++mi) {
#pragma unroll
    for (int r = 0; r < 4; ++r) {
      int grow = m0 + wm * 32 + mi * 16 + q * 4 + r;
      if (grow < count) {
        int f = rowmap[e * CAP + grow];
        float w = tw[f];
        int t = f >> 1;
#pragma unroll
        for (int ni = 0; ni < 2; ++ni) {
          int col = n0 + wn * 32 + ni * 16 + lm;
          atomicAdd(&out[(size_t)t * HD + col], w * acc[mi][ni][r]);
        }
      }
    }
  }
}

extern "C" void kernel_launch(void* const* d_in, const int* in_sizes, int n_in,
                              void* d_out, int out_size, void* d_ws, size_t ws_size,
                              hipStream_t stream) {
  const float* hidden = (const float*)d_in[0];
  const float* w1 = (const float*)d_in[1];
  const float* w2 = (const float*)d_in[2];
  const float* tw = (const float*)d_in[3];
  const int* ids = (const int*)d_in[4];
  float* out = (float*)d_out;

  char* p = (char*)d_ws;
  auto alloc = [&](size_t b) { char* r = p; p += (b + 255) & ~(size_t)255; return r; };
  u16* bw1 = (u16*)alloc((size_t)NE * 2 * ID * HD * 2);   // 46.1 MB (interleaved rows)
  u16* bw2 = (u16*)alloc((size_t)NE * HD * ID * 2);        // 23.1 MB
  u16* bx = (u16*)alloc((size_t)TT * HD * 2);              // 4.2 MB
  u16* hbuf = (u16*)alloc((size_t)NE * CAP * ID * 2);      // 23.1 MB
  int* rowmap = (int*)alloc((size_t)NE * CAP * 4);
  int* flatpos = (int*)alloc((size_t)TT * 2 * 4);
  int* counts = (int*)alloc((size_t)NE * 4);

  // single fused prep launch (w1 il-cvt | w2 cvt | x cvt + out zero)
  prep_kernel<<<W1_BLKS + W2_BLKS + X_BLKS, 256, 0, stream>>>(
      (const float4*)w1, (ushort4*)bw1, (const float4*)w2, (ushort4*)bw2,
      (const float4*)hidden, (ushort4*)bx, (float4*)out);

  route_kernel<<<1, 256, 0, stream>>>(ids, rowmap, flatpos, counts);

  // GEMM1 + SiLU: hbuf = silu(x.w1g^T) * (x.w1u^T)
  gemm1_kernel<<<dim3(NE, CAP / 64, 2 * ID / 128), 256, 0, stream>>>(
      bx, bw1, hbuf, rowmap, counts);

  // GEMM2 + combine: out[t,:] += w * (act . w2^T)
  gemm2_kernel<<<dim3(NE, CAP / 64, HD / 64), 256, 0, stream>>>(
      hbuf, bw2, out, rowmap, counts, tw);
}